// Round 4
// baseline (235.865 us; speedup 1.0000x reference)
//
#include <hip/hip_runtime.h>
#include <math.h>

#define EPS 1e-8f

// Specialized geometry (matches setup_inputs): frames=64, height=23, width=24,
// tpf=552, hidden=1152, interval=1, ntok=35328.
#define TPF   552
#define HID   1152
#define NTOK  35328
#define WID   24
#define NCHAINW 2898   // 63 frames * 23 residues * 2 segments
#define NBLK  726      // 726*4 waves = 2904 = 2898 chains + 6 fill waves

// Chain trick: B2 of task (f,c) is row (f+1,c+24) == B1 of task (f,c+23).
// A wave walks 12 tasks at column stride 23, loading 12 A rows + 13 B rows
// (25 rows / 12 tasks vs 36 naive = 0.69x cache-hierarchy traffic). All rows
// live in registers (software-pipelined one step ahead); norms inline.

struct Row { float4 a, b, c, d; float2 e; };  // 18 floats/lane = one 1152-row per wave

__device__ __forceinline__ Row load_row(const float* __restrict__ p, int lane) {
    Row r;
    const float4* p4 = (const float4*)p;
    r.a = p4[lane];       r.b = p4[lane + 64];
    r.c = p4[lane + 128]; r.d = p4[lane + 192];
    r.e = ((const float2*)(p + 1024))[lane];
    return r;
}

__device__ __forceinline__ float dotrr(const Row& x, const Row& y) {
    float s = 0.f;
    s = fmaf(x.a.x, y.a.x, s); s = fmaf(x.a.y, y.a.y, s);
    s = fmaf(x.a.z, y.a.z, s); s = fmaf(x.a.w, y.a.w, s);
    s = fmaf(x.b.x, y.b.x, s); s = fmaf(x.b.y, y.b.y, s);
    s = fmaf(x.b.z, y.b.z, s); s = fmaf(x.b.w, y.b.w, s);
    s = fmaf(x.c.x, y.c.x, s); s = fmaf(x.c.y, y.c.y, s);
    s = fmaf(x.c.z, y.c.z, s); s = fmaf(x.c.w, y.c.w, s);
    s = fmaf(x.d.x, y.d.x, s); s = fmaf(x.d.y, y.d.y, s);
    s = fmaf(x.d.z, y.d.z, s); s = fmaf(x.d.w, y.d.w, s);
    s = fmaf(x.e.x, y.e.x, s); s = fmaf(x.e.y, y.e.y, s);
    return s;
}

__device__ __forceinline__ float reduce64(float v) {
    #pragma unroll
    for (int m = 1; m < 64; m <<= 1) v += __shfl_xor(v, m, 64);
    return v;
}

__global__ void __launch_bounds__(256) simdiff_chain_kernel(
    const float* __restrict__ x,
    const int* __restrict__ p_frames,
    const int* __restrict__ p_width,
    const int* __restrict__ p_interval,
    float* __restrict__ out)
{
    const int frames   = *p_frames;
    const int width    = *p_width;
    const int interval = *p_interval;
    const int lane     = threadIdx.x & 63;
    const int w        = blockIdx.x * (blockDim.x >> 6) + (threadIdx.x >> 6);

    const bool spec = (frames == 64) && (width == WID) && (interval == 1);

    if (spec) {
        if (w >= NCHAINW) {
            // 6 spare waves: fill frame 63 outputs (all invalid -> -1)
            for (int i = (w - NCHAINW) * 64 + lane; i < 2 * TPF; i += 6 * 64) {
                if (i < TPF) out[63 * TPF + i]          = -1.f;
                else         out[NTOK + 63 * TPF + (i - TPF)] = -1.f;
            }
            return;
        }
        const int seg    = w & 1;
        const int chain  = w >> 1;
        const int f      = chain / 23;           // 0..62
        const int c0     = chain - f * 23;       // 0..22
        const int cstart = c0 + 276 * seg;       // seg0: 0..22, seg1: 276..298

        const float* xf  = x + (size_t)(f * TPF) * HID;
        const float* xf1 = x + (size_t)((f + 1) * TPF) * HID;

        Row bcur = load_row(xf1 + (size_t)(cstart + 1)  * HID, lane);   // b_0
        Row bnxt = load_row(xf1 + (size_t)(cstart + 24) * HID, lane);   // b_1
        Row acur = load_row(xf  + (size_t)cstart        * HID, lane);   // a_0
        float nbcur = reduce64(dotrr(bcur, bcur));

        #pragma unroll
        for (int j = 0; j < 12; ++j) {
            const int c = cstart + 23 * j;

            // prefetch next step's rows (wave-uniform predicates)
            Row anxt = {}; Row bn2 = {};
            if (j < 11) {
                anxt = load_row(xf + (size_t)(c + 23) * HID, lane);     // a_{j+1}
                const int b2col = c + 47;                               // b_{j+2} col
                if (b2col < TPF)
                    bn2 = load_row(xf1 + (size_t)b2col * HID, lane);
            }

            float na    = reduce64(dotrr(acur, acur));
            float d1    = reduce64(dotrr(acur, bcur));
            float d2    = reduce64(dotrr(acur, bnxt));
            float nbnxt = reduce64(dotrr(bnxt, bnxt));

            if (lane == 0) {
                const int t  = f * TPF + c;
                const float sa = fmaxf(sqrtf(na), EPS);
                out[t]        = (c < TPF - 1)
                    ? d1 / (sa * fmaxf(sqrtf(nbcur), EPS)) : -1.f;
                out[NTOK + t] = (c < TPF - WID)
                    ? d2 / (sa * fmaxf(sqrtf(nbnxt), EPS)) : -1.f;
            }
            nbcur = nbnxt; acur = anxt; bcur = bnxt; bnxt = bn2;
        }
        return;
    }

    // ---------- generic fallback (params mismatch), grid-stride ----------
    const int ntok    = NTOK;  // host only routes here when ntok==35328,hidden==1152
    const int tpf     = ntok / frames;
    const int valid_f = frames - interval;
    const int stride  = gridDim.x * (blockDim.x >> 6);
    for (int task = w; task < ntok; task += stride) {
        const int f = task / tpf;
        const int i = task - f * tpf;
        const bool rv = (f < valid_f) && (i < tpf - 1);
        const bool dv = (f < valid_f) && (i < tpf - width);
        float out_r = -1.f, out_d = -1.f;
        if (rv || dv) {
            const float* A  = x + (size_t)task * HID;
            const float* B1 = rv ? x + (size_t)((f + interval) * tpf + i + 1) * HID : A;
            const float* B2 = dv ? x + (size_t)((f + interval) * tpf + i + width) * HID : A;
            Row a = load_row(A, lane), b1 = load_row(B1, lane), b2 = load_row(B2, lane);
            float na  = reduce64(dotrr(a, a));
            float nb1 = reduce64(dotrr(b1, b1));
            float nb2 = reduce64(dotrr(b2, b2));
            float d1  = reduce64(dotrr(a, b1));
            float d2  = reduce64(dotrr(a, b2));
            const float sa = fmaxf(sqrtf(na), EPS);
            if (rv) out_r = d1 / (sa * fmaxf(sqrtf(nb1), EPS));
            if (dv) out_d = d2 / (sa * fmaxf(sqrtf(nb2), EPS));
        }
        if (lane == 0) {
            out[task]        = out_r;
            out[ntok + task] = out_d;
        }
    }
}

// Fully generic kernel for unexpected host-side sizes.
__global__ void __launch_bounds__(256) simdiff_generic_kernel(
    const float* __restrict__ x,
    const int* __restrict__ p_frames,
    const int* __restrict__ p_width,
    const int* __restrict__ p_interval,
    float* __restrict__ out,
    int ntok, int hidden)
{
    const int frames   = *p_frames;
    const int width    = *p_width;
    const int interval = *p_interval;
    const int tpf      = ntok / frames;
    const int valid_f  = frames - interval;
    const int lane     = threadIdx.x & 63;
    const int stride   = gridDim.x * (blockDim.x >> 6);
    const int nvec     = hidden >> 2;

    for (int task = blockIdx.x * (blockDim.x >> 6) + (threadIdx.x >> 6);
         task < ntok; task += stride) {
        const int f = task / tpf;
        const int i = task - f * tpf;
        const bool rv = (f < valid_f) && (i < tpf - 1);
        const bool dv = (f < valid_f) && (i < tpf - width);
        float out_r = -1.f, out_d = -1.f;
        if (rv || dv) {
            const float4* A  = (const float4*)(x + (size_t)task * hidden);
            const float4* B1 = rv ? (const float4*)(x + (size_t)((f + interval) * tpf + i + 1) * hidden) : A;
            const float4* B2 = dv ? (const float4*)(x + (size_t)((f + interval) * tpf + i + width) * hidden) : A;
            float na2 = 0.f, nb1 = 0.f, nb2 = 0.f, d1 = 0.f, d2 = 0.f;
            for (int v = lane; v < nvec; v += 64) {
                const float4 a = A[v];
                na2 = fmaf(a.x,a.x, fmaf(a.y,a.y, fmaf(a.z,a.z, fmaf(a.w,a.w, na2))));
                const float4 b = B1[v];
                nb1 = fmaf(b.x,b.x, fmaf(b.y,b.y, fmaf(b.z,b.z, fmaf(b.w,b.w, nb1))));
                d1  = fmaf(a.x,b.x, fmaf(a.y,b.y, fmaf(a.z,b.z, fmaf(a.w,b.w, d1))));
                const float4 cc = B2[v];
                nb2 = fmaf(cc.x,cc.x, fmaf(cc.y,cc.y, fmaf(cc.z,cc.z, fmaf(cc.w,cc.w, nb2))));
                d2  = fmaf(a.x,cc.x, fmaf(a.y,cc.y, fmaf(a.z,cc.z, fmaf(a.w,cc.w, d2))));
            }
            #pragma unroll
            for (int m = 1; m < 64; m <<= 1) {
                na2 += __shfl_xor(na2, m, 64);
                nb1 += __shfl_xor(nb1, m, 64);
                nb2 += __shfl_xor(nb2, m, 64);
                d1  += __shfl_xor(d1, m, 64);
                d2  += __shfl_xor(d2, m, 64);
            }
            const float sa = fmaxf(sqrtf(na2), EPS);
            if (rv) out_r = d1 / (sa * fmaxf(sqrtf(nb1), EPS));
            if (dv) out_d = d2 / (sa * fmaxf(sqrtf(nb2), EPS));
        }
        if (lane == 0) {
            out[task]        = out_r;
            out[ntok + task] = out_d;
        }
    }
}

extern "C" void kernel_launch(void* const* d_in, const int* in_sizes, int n_in,
                              void* d_out, int out_size, void* d_ws, size_t ws_size,
                              hipStream_t stream) {
    const float* x        = (const float*)d_in[0];
    const int* p_frames   = (const int*)d_in[1];
    const int* p_width    = (const int*)d_in[3];
    const int* p_interval = (const int*)d_in[4];
    float* out            = (float*)d_out;

    const int ntok   = out_size / 2;
    const int hidden = in_sizes[0] / ntok;

    if (ntok == NTOK && hidden == HID) {
        simdiff_chain_kernel<<<NBLK, 256, 0, stream>>>(
            x, p_frames, p_width, p_interval, out);
    } else {
        const int blocks = (ntok + 3) / 4;
        simdiff_generic_kernel<<<blocks, 256, 0, stream>>>(
            x, p_frames, p_width, p_interval, out, ntok, hidden);
    }
}

// Round 5
// 232.167 us; speedup vs baseline: 1.0159x; 1.0159x over previous
//
#include <hip/hip_runtime.h>
#include <math.h>

#define EPS 1e-8f

// Specialized geometry: frames=64, height=23, width=24 -> tpf=552, hidden=1152,
// interval=1, ntok=35328.
#define TPF   552
#define HID   1152
#define NTOK  35328
#define WID   24

// Pair trick: tasks (f,c) and (f,c+23) share row (f+1,c+24)
// (down-partner of c == right-partner of c+23). One wave handles the pair:
// 5 row loads / 2 tasks (vs 6 naive) = 0.83x traffic, fully straight-line
// (all loads issued up front) so R2's latency hiding is preserved.
// Pairs: per frame f in 0..62, base=46k (k=0..11), j=0..22 -> (base+j, base+j+23).
#define PAIRS_PER_FRAME 276          // 12 * 23
#define NPAIRW  17388                // 63 frames * 276
#define NFILLW  20                   // frame-63 fill: 1104 outputs
#define NWAVES  17408                // 4352 blocks * 4 waves
#define NBLK    4352

struct Row { float4 a, b, c, d; float2 e; };  // 18 floats/lane = 1152/row/wave

__device__ __forceinline__ Row load_row(const float* __restrict__ p, int lane) {
    Row r;
    const float4* p4 = (const float4*)p;
    r.a = p4[lane];       r.b = p4[lane + 64];
    r.c = p4[lane + 128]; r.d = p4[lane + 192];
    r.e = ((const float2*)(p + 1024))[lane];
    return r;
}

__device__ __forceinline__ float dotrr(const Row& x, const Row& y) {
    float s = 0.f;
    s = fmaf(x.a.x, y.a.x, s); s = fmaf(x.a.y, y.a.y, s);
    s = fmaf(x.a.z, y.a.z, s); s = fmaf(x.a.w, y.a.w, s);
    s = fmaf(x.b.x, y.b.x, s); s = fmaf(x.b.y, y.b.y, s);
    s = fmaf(x.b.z, y.b.z, s); s = fmaf(x.b.w, y.b.w, s);
    s = fmaf(x.c.x, y.c.x, s); s = fmaf(x.c.y, y.c.y, s);
    s = fmaf(x.c.z, y.c.z, s); s = fmaf(x.c.w, y.c.w, s);
    s = fmaf(x.d.x, y.d.x, s); s = fmaf(x.d.y, y.d.y, s);
    s = fmaf(x.d.z, y.d.z, s); s = fmaf(x.d.w, y.d.w, s);
    s = fmaf(x.e.x, y.e.x, s); s = fmaf(x.e.y, y.e.y, s);
    return s;
}

__device__ __forceinline__ float reduce64(float v) {
    #pragma unroll
    for (int m = 1; m < 64; m <<= 1) v += __shfl_xor(v, m, 64);
    return v;
}

__global__ void __launch_bounds__(256) simdiff_pair_kernel(
    const float* __restrict__ x,
    const int* __restrict__ p_frames,
    const int* __restrict__ p_width,
    const int* __restrict__ p_interval,
    float* __restrict__ out)
{
    const int frames   = *p_frames;
    const int width    = *p_width;
    const int interval = *p_interval;
    const int lane     = threadIdx.x & 63;
    const int w        = blockIdx.x * (blockDim.x >> 6) + (threadIdx.x >> 6);

    const bool spec = (frames == 64) && (width == WID) && (interval == 1);

    if (spec) {
        if (w >= NPAIRW) {
            // fill frame 63 (all invalid -> -1): 2*TPF = 1104 outputs
            for (int i = (w - NPAIRW) * 64 + lane; i < 2 * TPF; i += NFILLW * 64) {
                if (i < TPF) out[63 * TPF + i]                = -1.f;
                else         out[NTOK + 63 * TPF + (i - TPF)] = -1.f;
            }
            return;
        }
        const int f    = w / PAIRS_PER_FRAME;              // 0..62
        const int p    = w - f * PAIRS_PER_FRAME;          // 0..275
        const int k    = p / 23;                           // 0..11
        const int j    = p - k * 23;                       // 0..22
        const int c1   = 46 * k + j;                       // 0..528
        const int c2   = c1 + 23;                          // 23..551

        const bool dv1 = (c1 < TPF - WID);   // down(c1); right(c1) always valid (c1<=528)
        const bool rv2 = (c2 < TPF - 1);     // right(c2); invalid iff c2==551 iff c1==528
        const bool dv2 = (c2 < TPF - WID);   // down(c2)

        const float* xf  = x + (size_t)(f * TPF) * HID;
        const float* xf1 = x + (size_t)((f + 1) * TPF) * HID;

        const float* pA1 = xf  + (size_t)c1 * HID;
        const float* pA2 = xf  + (size_t)c2 * HID;
        const float* pB1 = xf1 + (size_t)(c1 + 1) * HID;
        const float* pBs = (dv1 || rv2) ? xf1 + (size_t)(c1 + WID) * HID : pA1;  // shared
        const float* pB3 = dv2          ? xf1 + (size_t)(c2 + WID) * HID : pA1;

        // ---- all 5 row loads issued straight-line ----
        const Row A1 = load_row(pA1, lane);
        const Row A2 = load_row(pA2, lane);
        const Row B1 = load_row(pB1, lane);
        const Row Bs = load_row(pBs, lane);
        const Row B3 = load_row(pB3, lane);

        // ---- 9 reductions (independent butterflies) ----
        float na1 = reduce64(dotrr(A1, A1));
        float na2 = reduce64(dotrr(A2, A2));
        float nb1 = reduce64(dotrr(B1, B1));
        float nbs = reduce64(dotrr(Bs, Bs));
        float nb3 = reduce64(dotrr(B3, B3));
        float d11 = reduce64(dotrr(A1, B1));   // right(c1)
        float d1s = reduce64(dotrr(A1, Bs));   // down (c1)
        float d2s = reduce64(dotrr(A2, Bs));   // right(c2)
        float d23 = reduce64(dotrr(A2, B3));   // down (c2)

        if (lane == 0) {
            const int t1 = f * TPF + c1;
            const int t2 = f * TPF + c2;
            const float sa1 = fmaxf(sqrtf(na1), EPS);
            const float sa2 = fmaxf(sqrtf(na2), EPS);
            const float sb1 = fmaxf(sqrtf(nb1), EPS);
            const float sbs = fmaxf(sqrtf(nbs), EPS);
            const float sb3 = fmaxf(sqrtf(nb3), EPS);
            out[t1]        = d11 / (sa1 * sb1);                    // right(c1) always valid
            out[NTOK + t1] = dv1 ? d1s / (sa1 * sbs) : -1.f;       // down(c1)
            out[t2]        = rv2 ? d2s / (sa2 * sbs) : -1.f;       // right(c2)
            out[NTOK + t2] = dv2 ? d23 / (sa2 * sb3) : -1.f;       // down(c2)
        }
        return;
    }

    // ---------- generic fallback (device-param mismatch), grid-stride ----------
    const int ntok    = NTOK;
    const int tpf     = ntok / frames;
    const int valid_f = frames - interval;
    const int stride  = gridDim.x * (blockDim.x >> 6);
    for (int task = w; task < ntok; task += stride) {
        const int f = task / tpf;
        const int i = task - f * tpf;
        const bool rv = (f < valid_f) && (i < tpf - 1);
        const bool dv = (f < valid_f) && (i < tpf - width);
        float out_r = -1.f, out_d = -1.f;
        if (rv || dv) {
            const float* A  = x + (size_t)task * HID;
            const float* B1 = rv ? x + (size_t)((f + interval) * tpf + i + 1) * HID : A;
            const float* B2 = dv ? x + (size_t)((f + interval) * tpf + i + width) * HID : A;
            Row a = load_row(A, lane), b1 = load_row(B1, lane), b2 = load_row(B2, lane);
            float na  = reduce64(dotrr(a, a));
            float nb1 = reduce64(dotrr(b1, b1));
            float nb2 = reduce64(dotrr(b2, b2));
            float d1  = reduce64(dotrr(a, b1));
            float d2  = reduce64(dotrr(a, b2));
            const float sa = fmaxf(sqrtf(na), EPS);
            if (rv) out_r = d1 / (sa * fmaxf(sqrtf(nb1), EPS));
            if (dv) out_d = d2 / (sa * fmaxf(sqrtf(nb2), EPS));
        }
        if (lane == 0) {
            out[task]        = out_r;
            out[ntok + task] = out_d;
        }
    }
}

// Fully generic kernel for unexpected host-side sizes.
__global__ void __launch_bounds__(256) simdiff_generic_kernel(
    const float* __restrict__ x,
    const int* __restrict__ p_frames,
    const int* __restrict__ p_width,
    const int* __restrict__ p_interval,
    float* __restrict__ out,
    int ntok, int hidden)
{
    const int frames   = *p_frames;
    const int width    = *p_width;
    const int interval = *p_interval;
    const int tpf      = ntok / frames;
    const int valid_f  = frames - interval;
    const int lane     = threadIdx.x & 63;
    const int stride   = gridDim.x * (blockDim.x >> 6);
    const int nvec     = hidden >> 2;

    for (int task = blockIdx.x * (blockDim.x >> 6) + (threadIdx.x >> 6);
         task < ntok; task += stride) {
        const int f = task / tpf;
        const int i = task - f * tpf;
        const bool rv = (f < valid_f) && (i < tpf - 1);
        const bool dv = (f < valid_f) && (i < tpf - width);
        float out_r = -1.f, out_d = -1.f;
        if (rv || dv) {
            const float4* A  = (const float4*)(x + (size_t)task * hidden);
            const float4* B1 = rv ? (const float4*)(x + (size_t)((f + interval) * tpf + i + 1) * hidden) : A;
            const float4* B2 = dv ? (const float4*)(x + (size_t)((f + interval) * tpf + i + width) * hidden) : A;
            float na2 = 0.f, nb1 = 0.f, nb2 = 0.f, d1 = 0.f, d2 = 0.f;
            for (int v = lane; v < nvec; v += 64) {
                const float4 a = A[v];
                na2 = fmaf(a.x,a.x, fmaf(a.y,a.y, fmaf(a.z,a.z, fmaf(a.w,a.w, na2))));
                const float4 b = B1[v];
                nb1 = fmaf(b.x,b.x, fmaf(b.y,b.y, fmaf(b.z,b.z, fmaf(b.w,b.w, nb1))));
                d1  = fmaf(a.x,b.x, fmaf(a.y,b.y, fmaf(a.z,b.z, fmaf(a.w,b.w, d1))));
                const float4 cc = B2[v];
                nb2 = fmaf(cc.x,cc.x, fmaf(cc.y,cc.y, fmaf(cc.z,cc.z, fmaf(cc.w,cc.w, nb2))));
                d2  = fmaf(a.x,cc.x, fmaf(a.y,cc.y, fmaf(a.z,cc.z, fmaf(a.w,cc.w, d2))));
            }
            #pragma unroll
            for (int m = 1; m < 64; m <<= 1) {
                na2 += __shfl_xor(na2, m, 64);
                nb1 += __shfl_xor(nb1, m, 64);
                nb2 += __shfl_xor(nb2, m, 64);
                d1  += __shfl_xor(d1, m, 64);
                d2  += __shfl_xor(d2, m, 64);
            }
            const float sa = fmaxf(sqrtf(na2), EPS);
            if (rv) out_r = d1 / (sa * fmaxf(sqrtf(nb1), EPS));
            if (dv) out_d = d2 / (sa * fmaxf(sqrtf(nb2), EPS));
        }
        if (lane == 0) {
            out[task]        = out_r;
            out[ntok + task] = out_d;
        }
    }
}

extern "C" void kernel_launch(void* const* d_in, const int* in_sizes, int n_in,
                              void* d_out, int out_size, void* d_ws, size_t ws_size,
                              hipStream_t stream) {
    const float* x        = (const float*)d_in[0];
    const int* p_frames   = (const int*)d_in[1];
    const int* p_width    = (const int*)d_in[3];
    const int* p_interval = (const int*)d_in[4];
    float* out            = (float*)d_out;

    const int ntok   = out_size / 2;
    const int hidden = in_sizes[0] / ntok;

    if (ntok == NTOK && hidden == HID) {
        simdiff_pair_kernel<<<NBLK, 256, 0, stream>>>(
            x, p_frames, p_width, p_interval, out);
    } else {
        const int blocks = (ntok + 3) / 4;
        simdiff_generic_kernel<<<blocks, 256, 0, stream>>>(
            x, p_frames, p_width, p_interval, out, ntok, hidden);
    }
}